// Round 2
// baseline (137.377 us; speedup 1.0000x reference)
//
#include <hip/hip_runtime.h>
#include <math.h>

typedef __attribute__((ext_vector_type(4))) float f32x4;
typedef __attribute__((ext_vector_type(8))) short s16x8;

constexpr int B_ = 8, C_ = 384, N_ = 1024, NH_ = 8, D_ = 48;
constexpr float SCALE_ = 0.14433756729740643f;   // 1/sqrt(48)
constexpr float LOG2E_ = 1.4426950408889634f;
// Q is pre-scaled by SCALE_*LOG2E_ in qkv epilogue; attn computes exp2(s - 8*log2e)
constexpr float EXP_BIAS_ = 8.0f * LOG2E_;       // 11.541560...

__device__ __forceinline__ unsigned short f2bf(float f) {
    unsigned u = __builtin_bit_cast(unsigned, f);
    u += 0x7fff + ((u >> 16) & 1);           // round-to-nearest-even
    return (unsigned short)(u >> 16);
}
__device__ __forceinline__ float fexp2(float x) {
#if __has_builtin(__builtin_amdgcn_exp2f)
    return __builtin_amdgcn_exp2f(x);
#else
    return exp2f(x);
#endif
}
// pack two f32 -> 2xbf16 in one u32 (low = a, high = b)
__device__ __forceinline__ unsigned pk_bf16(float a, float b) {
    unsigned r;
    asm("v_cvt_pk_bf16_f32 %0, %1, %2" : "=v"(r) : "v"(a), "v"(b));
    return r;
}

// ---------------------------------------------------------------------------
// Kernel 1: LayerNorm (float4 loads, LDS transpose, int4 stores) + weight cvt.
// ---------------------------------------------------------------------------
__global__ __launch_bounds__(256) void ln_cvt_kernel(const float* __restrict__ x,
                                                     const float* __restrict__ lnw,
                                                     const float* __restrict__ lnb,
                                                     const float* __restrict__ wq,
                                                     const float* __restrict__ wp,
                                                     unsigned short* __restrict__ t,
                                                     unsigned short* __restrict__ wqb,
                                                     unsigned short* __restrict__ wpb) {
    int tid = threadIdx.x;
    int gid = blockIdx.x * 256 + tid;
    for (int i = gid; i < 1152 * 384; i += 512 * 256) wqb[i] = f2bf(wq[i]);
    for (int i = gid; i < 384 * 384;  i += 512 * 256) wpb[i] = f2bf(wp[i]);

    __shared__ float xs[384][17];
    __shared__ float wgt[384], bia[384];
    int b  = blockIdx.x >> 6;
    int n0 = (blockIdx.x & 63) << 4;
    for (int i = tid; i < 384; i += 256) { wgt[i] = lnw[i]; bia[i] = lnb[i]; }

    const float* xb = x + (size_t)b * 384 * 1024;
    #pragma unroll
    for (int k = 0; k < 6; k++) {
        int f = tid + k * 256;          // f < 1536
        int c = f >> 2, li = (f & 3) * 4;
        float4 v = *(const float4*)&xb[(size_t)c * 1024 + n0 + li];
        xs[c][li] = v.x; xs[c][li + 1] = v.y; xs[c][li + 2] = v.z; xs[c][li + 3] = v.w;
    }
    __syncthreads();

    int l = tid >> 4, part = tid & 15;
    float s = 0.f, sq = 0.f;
    #pragma unroll
    for (int j = 0; j < 24; j++) {
        float v = xs[part + j * 16][l];
        s += v; sq += v * v;
    }
    #pragma unroll
    for (int off = 1; off <= 8; off <<= 1) {
        s  += __shfl_xor(s,  off);
        sq += __shfl_xor(sq, off);
    }
    float mu   = s * (1.0f / 384.0f);
    float rstd = rsqrtf(sq * (1.0f / 384.0f) - mu * mu + 1e-6f);

    unsigned short* tp = t + (size_t)(b * 1024 + n0 + l) * 384 + part * 24;
    unsigned o32[12];
    #pragma unroll
    for (int m = 0; m < 12; m++) {
        int c0 = part * 24 + m * 2;
        unsigned lo = f2bf((xs[c0][l]     - mu) * rstd * wgt[c0]     + bia[c0]);
        unsigned hi = f2bf((xs[c0 + 1][l] - mu) * rstd * wgt[c0 + 1] + bia[c0 + 1]);
        o32[m] = lo | (hi << 16);
    }
    #pragma unroll
    for (int m = 0; m < 3; m++) {
        int4 pk = { (int)o32[m * 4], (int)o32[m * 4 + 1], (int)o32[m * 4 + 2], (int)o32[m * 4 + 3] };
        *(int4*)&tp[m * 8] = pk;
    }
}

// ---------------------------------------------------------------------------
// Kernel 2: QKV GEMM, 128x128 tile, BK=64. Grid (64, 9) = 576 blocks.
// ---------------------------------------------------------------------------
__global__ __launch_bounds__(256) void qkv_mfma(const unsigned short* __restrict__ t,
                                                const unsigned short* __restrict__ w,
                                                unsigned short* __restrict__ qn,
                                                unsigned short* __restrict__ kn,
                                                unsigned short* __restrict__ vt) {
    __shared__ __align__(16) unsigned short lds[128 * 72 * 2];        // 36864 B
    unsigned short (*As)[72]  = (unsigned short (*)[72])&lds[0];
    unsigned short (*Bs)[72]  = (unsigned short (*)[72])&lds[128 * 72];
    unsigned short (*Cs)[136] = (unsigned short (*)[136])&lds[0];     // 128*136 = 17408 <= 18432 shorts

    int tid = threadIdx.x;
    int m0 = blockIdx.x * 128;
    int jb = blockIdx.y;
    int j0 = jb * 128;
    int lane = tid & 63, wid = tid >> 6;
    int wr = wid >> 1, wc = wid & 1;
    int q16 = lane & 15, quad = lane >> 4;

    f32x4 acc[4][4] = {};

    // staging: 2 threads per row, 32 cols (4 int4) each, for both A and B
    const int srow = tid >> 1, sc = (tid & 1) * 32;
    for (int k0 = 0; k0 < 384; k0 += 64) {
        const unsigned short* ga = &t[(size_t)(m0 + srow) * 384 + k0 + sc];
        const unsigned short* gb = &w[(size_t)(j0 + srow) * 384 + k0 + sc];
        *(int4*)&As[srow][sc]      = *(const int4*)(ga);
        *(int4*)&As[srow][sc + 8]  = *(const int4*)(ga + 8);
        *(int4*)&As[srow][sc + 16] = *(const int4*)(ga + 16);
        *(int4*)&As[srow][sc + 24] = *(const int4*)(ga + 24);
        *(int4*)&Bs[srow][sc]      = *(const int4*)(gb);
        *(int4*)&Bs[srow][sc + 8]  = *(const int4*)(gb + 8);
        *(int4*)&Bs[srow][sc + 16] = *(const int4*)(gb + 16);
        *(int4*)&Bs[srow][sc + 24] = *(const int4*)(gb + 24);
        __syncthreads();
        #pragma unroll
        for (int s = 0; s < 2; s++) {
            s16x8 af[4], bfr[4];
            #pragma unroll
            for (int mi = 0; mi < 4; mi++) af[mi]  = *(const s16x8*)&As[wr * 64 + mi * 16 + q16][s * 32 + quad * 8];
            #pragma unroll
            for (int ni = 0; ni < 4; ni++) bfr[ni] = *(const s16x8*)&Bs[wc * 64 + ni * 16 + q16][s * 32 + quad * 8];
            #pragma unroll
            for (int mi = 0; mi < 4; mi++)
                #pragma unroll
                for (int ni = 0; ni < 4; ni++)
                    acc[mi][ni] = __builtin_amdgcn_mfma_f32_16x16x32_bf16(af[mi], bfr[ni], acc[mi][ni], 0, 0, 0);
        }
        __syncthreads();
    }

    if (jb < 6) {
        // Q gets SCALE * log2e folded in (attn uses exp2 directly)
        const float sc0 = (jb < 3) ? SCALE_ * LOG2E_ : 1.0f;
        unsigned short* dst = (jb < 3) ? qn : kn;
        int coff = (jb < 3 ? jb : jb - 3) * 128;
        #pragma unroll
        for (int mi = 0; mi < 4; mi++)
            #pragma unroll
            for (int ni = 0; ni < 4; ni++)
                #pragma unroll
                for (int r = 0; r < 4; r++)
                    Cs[wr * 64 + mi * 16 + quad * 4 + r][wc * 64 + ni * 16 + q16] = f2bf(acc[mi][ni][r] * sc0);
        __syncthreads();
        #pragma unroll
        for (int i = tid; i < 2048; i += 256) {
            int rr = i >> 4, cc = (i & 15) * 8;
            int m = m0 + rr;
            int bsel = m >> 10, nn = m & 1023;
            *(int4*)&dst[(size_t)(bsel * 1024 + nn) * 384 + coff + cc] = *(const int4*)&Cs[rr][cc];
        }
    } else {
        #pragma unroll
        for (int mi = 0; mi < 4; mi++) {
            int m_base = m0 + wr * 64 + mi * 16 + quad * 4;
            int bb = m_base >> 10;
            int nn = m_base & 1023;
            #pragma unroll
            for (int ni = 0; ni < 4; ni++) {
                int c2 = (jb - 6) * 128 + wc * 64 + ni * 16 + q16;
                int head = c2 / 48;
                int dd = c2 - head * 48;
                f32x4 a = acc[mi][ni];
                size_t base = (((size_t)bb * 8 + head) * 48 + dd) * 1024 + nn;
                ushort4 v4 = { f2bf(a.x), f2bf(a.y), f2bf(a.z), f2bf(a.w) };
                *(ushort4*)&vt[base] = v4;
            }
        }
    }
}

// ---------------------------------------------------------------------------
// Kernel 3: flash attention. This round: KVBLK=128 (8 iters, barriers halved),
// swapped QK^T (P regs hold consecutive k per fixed q -> cvt_pk + b64 P-writes,
// scalar row-sum), pads zeroed once, V-frags hoisted per half.
// Grid (8, NH, B) = 512 blocks. LDS 72.2 KB -> 2 blocks/CU (matches grid).
// ---------------------------------------------------------------------------
__global__ __launch_bounds__(256) void attn_mfma(const unsigned short* __restrict__ qn,
                                                 const unsigned short* __restrict__ kn,
                                                 const unsigned short* __restrict__ vt,
                                                 unsigned short* __restrict__ ao) {
    __shared__ __align__(16) unsigned short Ks[2][128][72];   // K chunks; Ks[0] doubles as Q/out buffer
    __shared__ __align__(16) unsigned short Vt[2][48][136];   // V^T chunks [d][n]
    __shared__ __align__(16) unsigned short Ps[4][16][72];    // per-wave P half-tiles [q][k]

    unsigned short (*Kflat)[72] = (unsigned short (*)[72])&Ks[0][0][0];  // 128 rows

    int tid = threadIdx.x, lane = tid & 63, wid = tid >> 6;
    int q16 = lane & 15, quad = lane >> 4;
    int qt = blockIdx.x, h = blockIdx.y, b = blockIdx.z;
    const unsigned short* qp = qn + (size_t)b * 1024 * 384 + h * 48;
    const unsigned short* kp = kn + (size_t)b * 1024 * 384 + h * 48;
    const unsigned short* vp = vt + ((size_t)b * NH_ + h) * 48 * N_;

    int4 z4 = {0, 0, 0, 0};

    // stage Q (128 x 48) into flat Ks[0]; zero d-pad cols 48..63
    {
        int r = tid >> 1, off = (tid & 1) * 24;
        const unsigned short* gp = qp + (size_t)(qt * 128 + r) * 384 + off;
        *(int4*)&Kflat[r][off]      = *(const int4*)gp;
        *(int4*)&Kflat[r][off + 8]  = *(const int4*)(gp + 8);
        *(int4*)&Kflat[r][off + 16] = *(const int4*)(gp + 16);
        if ((tid & 1) == 0) { *(int4*)&Kflat[r][48] = z4; *(int4*)&Kflat[r][56] = z4; }
    }
    __syncthreads();

    s16x8 qf[2][2];
    #pragma unroll
    for (int g = 0; g < 2; g++) {
        qf[g][0] = *(const s16x8*)&Kflat[wid * 32 + g * 16 + q16][quad * 8];
        qf[g][1] = *(const s16x8*)&Kflat[wid * 32 + g * 16 + q16][32 + quad * 8];
    }
    // zero Ks[1] pad cols 48..63 once (staging never touches them; Ks[0] pad came from Q stage)
    *(int4*)&Ks[1][tid >> 1][48 + (tid & 1) * 8] = z4;
    __syncthreads();   // Q reads done before K staging overwrites

    // staging roles (all 256 threads do both K and V):
    const int kr = tid >> 1, koff = (tid & 1) * 24;     // K: 2 thr/row, 3 int4
    const int vr0 = tid >> 4, vc0 = (tid & 15) * 8;     // V: 3 int4 at rows vr0, +16, +32

    // prologue: chunk 0 into buffer 0
    {
        const unsigned short* gp = kp + (size_t)kr * 384 + koff;
        *(int4*)&Ks[0][kr][koff]      = *(const int4*)gp;
        *(int4*)&Ks[0][kr][koff + 8]  = *(const int4*)(gp + 8);
        *(int4*)&Ks[0][kr][koff + 16] = *(const int4*)(gp + 16);
        *(int4*)&Vt[0][vr0][vc0]      = *(const int4*)&vp[(size_t)vr0 * 1024 + vc0];
        *(int4*)&Vt[0][vr0 + 16][vc0] = *(const int4*)&vp[(size_t)(vr0 + 16) * 1024 + vc0];
        *(int4*)&Vt[0][vr0 + 32][vc0] = *(const int4*)&vp[(size_t)(vr0 + 32) * 1024 + vc0];
    }
    __syncthreads();

    f32x4 o[2][3] = {};
    float lr[2] = {0.f, 0.f};

    for (int kt = 0; kt < 8; kt++) {
        int cur = kt & 1;

        // (1) prefetch kt+1 into registers (6 x int4)
        int4 kpf0, kpf1, kpf2, vpf0, vpf1, vpf2;
        if (kt < 7) {
            const unsigned short* gp = kp + (size_t)((kt + 1) * 128 + kr) * 384 + koff;
            kpf0 = *(const int4*)gp;
            kpf1 = *(const int4*)(gp + 8);
            kpf2 = *(const int4*)(gp + 16);
            int nb0 = (kt + 1) * 128;
            vpf0 = *(const int4*)&vp[(size_t)vr0 * 1024 + nb0 + vc0];
            vpf1 = *(const int4*)&vp[(size_t)(vr0 + 16) * 1024 + nb0 + vc0];
            vpf2 = *(const int4*)&vp[(size_t)(vr0 + 32) * 1024 + nb0 + vc0];
        }

        // (2) compute on buffer cur: two 64-key halves
        #pragma unroll
        for (int hh = 0; hh < 2; hh++) {
            // QK^T swapped: s[g][nt4] holds P[k=16*(4hh+nt4)+quad*4+r][q=q16]
            f32x4 s[2][4];
            __builtin_amdgcn_s_setprio(1);
            #pragma unroll
            for (int nt4 = 0; nt4 < 4; nt4++) {
                int ntg = hh * 4 + nt4;
                s16x8 k0 = *(const s16x8*)&Ks[cur][ntg * 16 + q16][quad * 8];
                s16x8 k1 = *(const s16x8*)&Ks[cur][ntg * 16 + q16][32 + quad * 8];
                #pragma unroll
                for (int g = 0; g < 2; g++) {
                    f32x4 z = {};
                    z = __builtin_amdgcn_mfma_f32_16x16x32_bf16(k0, qf[g][0], z, 0, 0, 0);
                    z = __builtin_amdgcn_mfma_f32_16x16x32_bf16(k1, qf[g][1], z, 0, 0, 0);
                    s[g][nt4] = z;
                }
            }
            __builtin_amdgcn_s_setprio(0);

            // exp2 + per-lane row-sum (each lane owns q=q16, keys quad*4+r)
            #pragma unroll
            for (int g = 0; g < 2; g++)
                #pragma unroll
                for (int nt4 = 0; nt4 < 4; nt4++) {
                    s[g][nt4].x = fexp2(s[g][nt4].x - EXP_BIAS_);
                    s[g][nt4].y = fexp2(s[g][nt4].y - EXP_BIAS_);
                    s[g][nt4].z = fexp2(s[g][nt4].z - EXP_BIAS_);
                    s[g][nt4].w = fexp2(s[g][nt4].w - EXP_BIAS_);
                    lr[g] += (s[g][nt4].x + s[g][nt4].y) + (s[g][nt4].z + s[g][nt4].w);
                }

            // hoisted V-frags for this half (c = 2*hh + c2)
            s16x8 vf[2][3];
            #pragma unroll
            for (int c2 = 0; c2 < 2; c2++)
                #pragma unroll
                for (int dt = 0; dt < 3; dt++)
                    vf[c2][dt] = *(const s16x8*)&Vt[cur][dt * 16 + q16][(2 * hh + c2) * 32 + quad * 8];

            #pragma unroll
            for (int g = 0; g < 2; g++) {
                // pack P pairs -> 4 x ds_write_b64 into Ps[wid][q][k]
                #pragma unroll
                for (int n2 = 0; n2 < 4; n2++) {
                    unsigned lo = pk_bf16(s[g][n2].x, s[g][n2].y);
                    unsigned hi = pk_bf16(s[g][n2].z, s[g][n2].w);
                    uint2 pkw = { lo, hi };
                    *(uint2*)&Ps[wid][q16][n2 * 16 + quad * 4] = pkw;
                }
                #pragma unroll
                for (int c2 = 0; c2 < 2; c2++) {
                    s16x8 pfr = *(const s16x8*)&Ps[wid][q16][c2 * 32 + quad * 8];
                    __builtin_amdgcn_s_setprio(1);
                    #pragma unroll
                    for (int dt = 0; dt < 3; dt++)
                        o[g][dt] = __builtin_amdgcn_mfma_f32_16x16x32_bf16(vf[c2][dt], pfr, o[g][dt], 0, 0, 0);
                    __builtin_amdgcn_s_setprio(0);
                }
            }
        }

        // (3) write prefetch to buffer cur^1
        if (kt < 7) {
            int nb = cur ^ 1;
            *(int4*)&Ks[nb][kr][koff]      = kpf0;
            *(int4*)&Ks[nb][kr][koff + 8]  = kpf1;
            *(int4*)&Ks[nb][kr][koff + 16] = kpf2;
            *(int4*)&Vt[nb][vr0][vc0]      = vpf0;
            *(int4*)&Vt[nb][vr0 + 16][vc0] = vpf1;
            *(int4*)&Vt[nb][vr0 + 32][vc0] = vpf2;
        }
        // (4) one barrier per iteration
        __syncthreads();
    }

    // full row-sum: reduce across the 4 quads (lanes q16 + 16*quad)
    #pragma unroll
    for (int g = 0; g < 2; g++) {
        lr[g] += __shfl_xor(lr[g], 16);
        lr[g] += __shfl_xor(lr[g], 32);
    }

    // epilogue: o[g][dt][r] = O[q=q16][d=dt*16+quad*4+r] -> Kflat rows, b64 writes
    #pragma unroll
    for (int g = 0; g < 2; g++) {
        float inv = __builtin_amdgcn_rcpf(lr[g]);
        #pragma unroll
        for (int dt = 0; dt < 3; dt++) {
            f32x4 a = o[g][dt];
            unsigned u0 = (unsigned)f2bf(a.x * inv) | ((unsigned)f2bf(a.y * inv) << 16);
            unsigned u1 = (unsigned)f2bf(a.z * inv) | ((unsigned)f2bf(a.w * inv) << 16);
            uint2 pkw = { u0, u1 };
            *(uint2*)&Kflat[wid * 32 + g * 16 + q16][dt * 16 + quad * 4] = pkw;
        }
    }
    __syncthreads();

    {
        int r = tid >> 1, off = (tid & 1) * 24;
        unsigned short* dst = ao + ((size_t)b * 1024 + qt * 128 + r) * 384 + h * 48 + off;
        *(int4*)dst        = *(const int4*)&Kflat[r][off];
        *(int4*)(dst + 8)  = *(const int4*)&Kflat[r][off + 8];
        *(int4*)(dst + 16) = *(const int4*)&Kflat[r][off + 16];
    }
}

// ---------------------------------------------------------------------------
// Kernel 4: proj GEMM 64x64 tile, BK=64 + residual. Grid (128, 6) = 768 blocks.
// ---------------------------------------------------------------------------
__global__ __launch_bounds__(256) void proj_mfma(const unsigned short* __restrict__ ao,
                                                 const unsigned short* __restrict__ w,
                                                 const float* __restrict__ x,
                                                 float* __restrict__ out) {
    __shared__ __align__(16) unsigned short As[64][72];
    __shared__ __align__(16) unsigned short Bs[64][72];

    int tid = threadIdx.x;
    int m0 = blockIdx.x * 64;
    int j0 = blockIdx.y * 64;
    int lane = tid & 63, wid = tid >> 6;
    int wr = wid >> 1, wc = wid & 1;
    int q16 = lane & 15, quad = lane >> 4;

    f32x4 acc[2][2] = {};

    const int srow = tid >> 2, sc = (tid & 3) * 16;
    for (int k0 = 0; k0 < 384; k0 += 64) {
        const unsigned short* ga = &ao[(size_t)(m0 + srow) * 384 + k0 + sc];
        const unsigned short* gb = &w[(size_t)(j0 + srow) * 384 + k0 + sc];
        *(int4*)&As[srow][sc]     = *(const int4*)(ga);
        *(int4*)&As[srow][sc + 8] = *(const int4*)(ga + 8);
        *(int4*)&Bs[srow][sc]     = *(const int4*)(gb);
        *(int4*)&Bs[srow][sc + 8] = *(const int4*)(gb + 8);
        __syncthreads();
        #pragma unroll
        for (int s = 0; s < 2; s++) {
            s16x8 af[2], bfr[2];
            #pragma unroll
            for (int mi = 0; mi < 2; mi++) af[mi]  = *(const s16x8*)&As[wr * 32 + mi * 16 + q16][s * 32 + quad * 8];
            #pragma unroll
            for (int ni = 0; ni < 2; ni++) bfr[ni] = *(const s16x8*)&Bs[wc * 32 + ni * 16 + q16][s * 32 + quad * 8];
            #pragma unroll
            for (int mi = 0; mi < 2; mi++)
                #pragma unroll
                for (int ni = 0; ni < 2; ni++)
                    acc[mi][ni] = __builtin_amdgcn_mfma_f32_16x16x32_bf16(af[mi], bfr[ni], acc[mi][ni], 0, 0, 0);
        }
        __syncthreads();
    }

    #pragma unroll
    for (int mi = 0; mi < 2; mi++) {
        int m_base = m0 + wr * 32 + mi * 16 + quad * 4;
        int bb = m_base >> 10;
        int nn = m_base & 1023;
        #pragma unroll
        for (int ni = 0; ni < 2; ni++) {
            int col = j0 + wc * 32 + ni * 16 + q16;
            size_t idx = ((size_t)bb * 384 + col) * 1024 + nn;
            float4 xr = *(const float4*)&x[idx];
            f32x4 a = acc[mi][ni];
            float4 ov = { xr.x + a.x, xr.y + a.y, xr.z + a.z, xr.w + a.w };
            *(float4*)&out[idx] = ov;
        }
    }
}

// ---------------------------------------------------------------------------
extern "C" void kernel_launch(void* const* d_in, const int* in_sizes, int n_in,
                              void* d_out, int out_size, void* d_ws, size_t ws_size,
                              hipStream_t stream) {
    const float* x     = (const float*)d_in[0];
    const float* wqkv  = (const float*)d_in[1];
    const float* wproj = (const float*)d_in[2];
    const float* lnw   = (const float*)d_in[3];
    const float* lnb   = (const float*)d_in[4];
    float* out = (float*)d_out;

    unsigned short* ws16 = (unsigned short*)d_ws;
    size_t off = 0;
    unsigned short* t_bf  = ws16 + off; off += (size_t)8192 * 384;
    unsigned short* wq_bf = ws16 + off; off += (size_t)1152 * 384;
    unsigned short* wp_bf = ws16 + off; off += (size_t)384 * 384;
    unsigned short* qn    = ws16 + off; off += (size_t)8192 * 384;   // [b,n,384] pre-scaled by SCALE*log2e
    unsigned short* kn    = ws16 + off; off += (size_t)8192 * 384;   // [b,n,384]
    unsigned short* vt    = ws16 + off; off += (size_t)64 * 48 * 1024; // [b,h,d,n]
    unsigned short* ao_bf = ws16 + off; off += (size_t)8192 * 384;

    ln_cvt_kernel<<<512, 256, 0, stream>>>(x, lnw, lnb, wqkv, wproj, t_bf, wq_bf, wp_bf);
    qkv_mfma<<<dim3(64, 9), 256, 0, stream>>>(t_bf, wq_bf, qn, kn, vt);
    attn_mfma<<<dim3(8, NH_, B_), 256, 0, stream>>>(qn, kn, vt, ao_bf);
    proj_mfma<<<dim3(128, 6), 256, 0, stream>>>(ao_bf, wp_bf, x, out);
}

// Round 3
// 136.916 us; speedup vs baseline: 1.0034x; 1.0034x over previous
//
#include <hip/hip_runtime.h>
#include <math.h>

typedef __attribute__((ext_vector_type(4))) float f32x4;
typedef __attribute__((ext_vector_type(8))) short s16x8;

constexpr int B_ = 8, C_ = 384, N_ = 1024, NH_ = 8, D_ = 48;
constexpr float SCALE_ = 0.14433756729740643f;   // 1/sqrt(48)
constexpr float LOG2E_ = 1.4426950408889634f;
// Q is pre-scaled by SCALE_*LOG2E_ in qkv epilogue; attn computes exp2(s - 8*log2e)
constexpr float EXP_BIAS_ = 8.0f * LOG2E_;       // 11.541560...

__device__ __forceinline__ unsigned short f2bf(float f) {
    unsigned u = __builtin_bit_cast(unsigned, f);
    u += 0x7fff + ((u >> 16) & 1);           // round-to-nearest-even
    return (unsigned short)(u >> 16);
}
__device__ __forceinline__ float fexp2(float x) {
#if __has_builtin(__builtin_amdgcn_exp2f)
    return __builtin_amdgcn_exp2f(x);
#else
    return exp2f(x);
#endif
}
// pack two f32 -> 2xbf16 in one u32 (low = a, high = b)
__device__ __forceinline__ unsigned pk_bf16(float a, float b) {
    unsigned r;
    asm("v_cvt_pk_bf16_f32 %0, %1, %2" : "=v"(r) : "v"(a), "v"(b));
    return r;
}

// ---------------------------------------------------------------------------
// Kernel 1: LayerNorm (float4 loads, LDS transpose, int4 stores) + weight cvt.
// ---------------------------------------------------------------------------
__global__ __launch_bounds__(256) void ln_cvt_kernel(const float* __restrict__ x,
                                                     const float* __restrict__ lnw,
                                                     const float* __restrict__ lnb,
                                                     const float* __restrict__ wq,
                                                     const float* __restrict__ wp,
                                                     unsigned short* __restrict__ t,
                                                     unsigned short* __restrict__ wqb,
                                                     unsigned short* __restrict__ wpb) {
    int tid = threadIdx.x;
    int gid = blockIdx.x * 256 + tid;
    for (int i = gid; i < 1152 * 384; i += 512 * 256) wqb[i] = f2bf(wq[i]);
    for (int i = gid; i < 384 * 384;  i += 512 * 256) wpb[i] = f2bf(wp[i]);

    __shared__ float xs[384][17];
    __shared__ float wgt[384], bia[384];
    int b  = blockIdx.x >> 6;
    int n0 = (blockIdx.x & 63) << 4;
    for (int i = tid; i < 384; i += 256) { wgt[i] = lnw[i]; bia[i] = lnb[i]; }

    const float* xb = x + (size_t)b * 384 * 1024;
    #pragma unroll
    for (int k = 0; k < 6; k++) {
        int f = tid + k * 256;          // f < 1536
        int c = f >> 2, li = (f & 3) * 4;
        float4 v = *(const float4*)&xb[(size_t)c * 1024 + n0 + li];
        xs[c][li] = v.x; xs[c][li + 1] = v.y; xs[c][li + 2] = v.z; xs[c][li + 3] = v.w;
    }
    __syncthreads();

    int l = tid >> 4, part = tid & 15;
    float s = 0.f, sq = 0.f;
    #pragma unroll
    for (int j = 0; j < 24; j++) {
        float v = xs[part + j * 16][l];
        s += v; sq += v * v;
    }
    #pragma unroll
    for (int off = 1; off <= 8; off <<= 1) {
        s  += __shfl_xor(s,  off);
        sq += __shfl_xor(sq, off);
    }
    float mu   = s * (1.0f / 384.0f);
    float rstd = rsqrtf(sq * (1.0f / 384.0f) - mu * mu + 1e-6f);

    unsigned short* tp = t + (size_t)(b * 1024 + n0 + l) * 384 + part * 24;
    unsigned o32[12];
    #pragma unroll
    for (int m = 0; m < 12; m++) {
        int c0 = part * 24 + m * 2;
        unsigned lo = f2bf((xs[c0][l]     - mu) * rstd * wgt[c0]     + bia[c0]);
        unsigned hi = f2bf((xs[c0 + 1][l] - mu) * rstd * wgt[c0 + 1] + bia[c0 + 1]);
        o32[m] = lo | (hi << 16);
    }
    #pragma unroll
    for (int m = 0; m < 3; m++) {
        int4 pk = { (int)o32[m * 4], (int)o32[m * 4 + 1], (int)o32[m * 4 + 2], (int)o32[m * 4 + 3] };
        *(int4*)&tp[m * 8] = pk;
    }
}

// ---------------------------------------------------------------------------
// Kernel 2: QKV GEMM, 128x128 tile, BK=96 (4 k-steps, 48 MFMA/wave/phase).
// LDS 53.2 KB -> 3 blocks/CU (avoids m132 occupancy cliff). Grid (64, 9).
// ---------------------------------------------------------------------------
__global__ __launch_bounds__(256) void qkv_mfma(const unsigned short* __restrict__ t,
                                                const unsigned short* __restrict__ w,
                                                unsigned short* __restrict__ qn,
                                                unsigned short* __restrict__ kn,
                                                unsigned short* __restrict__ vt) {
    __shared__ __align__(16) unsigned short lds[128 * 104 * 2];       // 53248 B
    unsigned short (*As)[104] = (unsigned short (*)[104])&lds[0];
    unsigned short (*Bs)[104] = (unsigned short (*)[104])&lds[128 * 104];
    unsigned short (*Cs)[136] = (unsigned short (*)[136])&lds[0];     // 17408 <= 26624 shorts

    int tid = threadIdx.x;
    int m0 = blockIdx.x * 128;
    int jb = blockIdx.y;
    int j0 = jb * 128;
    int lane = tid & 63, wid = tid >> 6;
    int wr = wid >> 1, wc = wid & 1;
    int q16 = lane & 15, quad = lane >> 4;

    f32x4 acc[4][4] = {};

    // staging: 2 threads per row, 48 cols (6 int4) each, for both A and B
    const int srow = tid >> 1, sc = (tid & 1) * 48;
    for (int k0 = 0; k0 < 384; k0 += 96) {
        const unsigned short* ga = &t[(size_t)(m0 + srow) * 384 + k0 + sc];
        const unsigned short* gb = &w[(size_t)(j0 + srow) * 384 + k0 + sc];
        #pragma unroll
        for (int u = 0; u < 6; u++) *(int4*)&As[srow][sc + u * 8] = *(const int4*)(ga + u * 8);
        #pragma unroll
        for (int u = 0; u < 6; u++) *(int4*)&Bs[srow][sc + u * 8] = *(const int4*)(gb + u * 8);
        __syncthreads();
        #pragma unroll
        for (int s = 0; s < 3; s++) {
            s16x8 af[4], bfr[4];
            #pragma unroll
            for (int mi = 0; mi < 4; mi++) af[mi]  = *(const s16x8*)&As[wr * 64 + mi * 16 + q16][s * 32 + quad * 8];
            #pragma unroll
            for (int ni = 0; ni < 4; ni++) bfr[ni] = *(const s16x8*)&Bs[wc * 64 + ni * 16 + q16][s * 32 + quad * 8];
            #pragma unroll
            for (int mi = 0; mi < 4; mi++)
                #pragma unroll
                for (int ni = 0; ni < 4; ni++)
                    acc[mi][ni] = __builtin_amdgcn_mfma_f32_16x16x32_bf16(af[mi], bfr[ni], acc[mi][ni], 0, 0, 0);
        }
        __syncthreads();
    }

    if (jb < 6) {
        // Q gets SCALE * log2e folded in (attn uses exp2 directly)
        const float sc0 = (jb < 3) ? SCALE_ * LOG2E_ : 1.0f;
        unsigned short* dst = (jb < 3) ? qn : kn;
        int coff = (jb < 3 ? jb : jb - 3) * 128;
        #pragma unroll
        for (int mi = 0; mi < 4; mi++)
            #pragma unroll
            for (int ni = 0; ni < 4; ni++)
                #pragma unroll
                for (int r = 0; r < 4; r++)
                    Cs[wr * 64 + mi * 16 + quad * 4 + r][wc * 64 + ni * 16 + q16] = f2bf(acc[mi][ni][r] * sc0);
        __syncthreads();
        #pragma unroll
        for (int i = tid; i < 2048; i += 256) {
            int rr = i >> 4, cc = (i & 15) * 8;
            int m = m0 + rr;
            int bsel = m >> 10, nn = m & 1023;
            *(int4*)&dst[(size_t)(bsel * 1024 + nn) * 384 + coff + cc] = *(const int4*)&Cs[rr][cc];
        }
    } else {
        #pragma unroll
        for (int mi = 0; mi < 4; mi++) {
            int m_base = m0 + wr * 64 + mi * 16 + quad * 4;
            int bb = m_base >> 10;
            int nn = m_base & 1023;
            #pragma unroll
            for (int ni = 0; ni < 4; ni++) {
                int c2 = (jb - 6) * 128 + wc * 64 + ni * 16 + q16;
                int head = c2 / 48;
                int dd = c2 - head * 48;
                f32x4 a = acc[mi][ni];
                size_t base = (((size_t)bb * 8 + head) * 48 + dd) * 1024 + nn;
                ushort4 v4 = { f2bf(a.x), f2bf(a.y), f2bf(a.z), f2bf(a.w) };
                *(ushort4*)&vt[base] = v4;
            }
        }
    }
}

// ---------------------------------------------------------------------------
// Kernel 3: flash attention. KVBLK=128 (8 iters), swapped QK^T (P regs hold
// consecutive k per fixed q -> cvt_pk + b64 P-writes, scalar row-sum),
// pads zeroed once, V-frags hoisted per half. Grid (8, NH, B) = 512 blocks.
// ---------------------------------------------------------------------------
__global__ __launch_bounds__(256) void attn_mfma(const unsigned short* __restrict__ qn,
                                                 const unsigned short* __restrict__ kn,
                                                 const unsigned short* __restrict__ vt,
                                                 unsigned short* __restrict__ ao) {
    __shared__ __align__(16) unsigned short Ks[2][128][72];   // K chunks; Ks[0] doubles as Q/out buffer
    __shared__ __align__(16) unsigned short Vt[2][48][136];   // V^T chunks [d][n]
    __shared__ __align__(16) unsigned short Ps[4][16][72];    // per-wave P half-tiles [q][k]

    unsigned short (*Kflat)[72] = (unsigned short (*)[72])&Ks[0][0][0];  // 128 rows

    int tid = threadIdx.x, lane = tid & 63, wid = tid >> 6;
    int q16 = lane & 15, quad = lane >> 4;
    int qt = blockIdx.x, h = blockIdx.y, b = blockIdx.z;
    const unsigned short* qp = qn + (size_t)b * 1024 * 384 + h * 48;
    const unsigned short* kp = kn + (size_t)b * 1024 * 384 + h * 48;
    const unsigned short* vp = vt + ((size_t)b * NH_ + h) * 48 * N_;

    int4 z4 = {0, 0, 0, 0};

    // stage Q (128 x 48) into flat Ks[0]; zero d-pad cols 48..63
    {
        int r = tid >> 1, off = (tid & 1) * 24;
        const unsigned short* gp = qp + (size_t)(qt * 128 + r) * 384 + off;
        *(int4*)&Kflat[r][off]      = *(const int4*)gp;
        *(int4*)&Kflat[r][off + 8]  = *(const int4*)(gp + 8);
        *(int4*)&Kflat[r][off + 16] = *(const int4*)(gp + 16);
        if ((tid & 1) == 0) { *(int4*)&Kflat[r][48] = z4; *(int4*)&Kflat[r][56] = z4; }
    }
    __syncthreads();

    s16x8 qf[2][2];
    #pragma unroll
    for (int g = 0; g < 2; g++) {
        qf[g][0] = *(const s16x8*)&Kflat[wid * 32 + g * 16 + q16][quad * 8];
        qf[g][1] = *(const s16x8*)&Kflat[wid * 32 + g * 16 + q16][32 + quad * 8];
    }
    // zero Ks[1] pad cols 48..63 once (staging never touches them; Ks[0] pad came from Q stage)
    *(int4*)&Ks[1][tid >> 1][48 + (tid & 1) * 8] = z4;
    __syncthreads();   // Q reads done before K staging overwrites

    // staging roles (all 256 threads do both K and V):
    const int kr = tid >> 1, koff = (tid & 1) * 24;     // K: 2 thr/row, 3 int4
    const int vr0 = tid >> 4, vc0 = (tid & 15) * 8;     // V: 3 int4 at rows vr0, +16, +32

    // prologue: chunk 0 into buffer 0
    {
        const unsigned short* gp = kp + (size_t)kr * 384 + koff;
        *(int4*)&Ks[0][kr][koff]      = *(const int4*)gp;
        *(int4*)&Ks[0][kr][koff + 8]  = *(const int4*)(gp + 8);
        *(int4*)&Ks[0][kr][koff + 16] = *(const int4*)(gp + 16);
        *(int4*)&Vt[0][vr0][vc0]      = *(const int4*)&vp[(size_t)vr0 * 1024 + vc0];
        *(int4*)&Vt[0][vr0 + 16][vc0] = *(const int4*)&vp[(size_t)(vr0 + 16) * 1024 + vc0];
        *(int4*)&Vt[0][vr0 + 32][vc0] = *(const int4*)&vp[(size_t)(vr0 + 32) * 1024 + vc0];
    }
    __syncthreads();

    f32x4 o[2][3] = {};
    float lr[2] = {0.f, 0.f};

    for (int kt = 0; kt < 8; kt++) {
        int cur = kt & 1;

        // (1) prefetch kt+1 into registers (6 x int4)
        int4 kpf0, kpf1, kpf2, vpf0, vpf1, vpf2;
        if (kt < 7) {
            const unsigned short* gp = kp + (size_t)((kt + 1) * 128 + kr) * 384 + koff;
            kpf0 = *(const int4*)gp;
            kpf1 = *(const int4*)(gp + 8);
            kpf2 = *(const int4*)(gp + 16);
            int nb0 = (kt + 1) * 128;
            vpf0 = *(const int4*)&vp[(size_t)vr0 * 1024 + nb0 + vc0];
            vpf1 = *(const int4*)&vp[(size_t)(vr0 + 16) * 1024 + nb0 + vc0];
            vpf2 = *(const int4*)&vp[(size_t)(vr0 + 32) * 1024 + nb0 + vc0];
        }

        // (2) compute on buffer cur: two 64-key halves
        #pragma unroll
        for (int hh = 0; hh < 2; hh++) {
            // QK^T swapped: s[g][nt4] holds P[k=16*(4hh+nt4)+quad*4+r][q=q16]
            f32x4 s[2][4];
            __builtin_amdgcn_s_setprio(1);
            #pragma unroll
            for (int nt4 = 0; nt4 < 4; nt4++) {
                int ntg = hh * 4 + nt4;
                s16x8 k0 = *(const s16x8*)&Ks[cur][ntg * 16 + q16][quad * 8];
                s16x8 k1 = *(const s16x8*)&Ks[cur][ntg * 16 + q16][32 + quad * 8];
                #pragma unroll
                for (int g = 0; g < 2; g++) {
                    f32x4 z = {};
                    z = __builtin_amdgcn_mfma_f32_16x16x32_bf16(k0, qf[g][0], z, 0, 0, 0);
                    z = __builtin_amdgcn_mfma_f32_16x16x32_bf16(k1, qf[g][1], z, 0, 0, 0);
                    s[g][nt4] = z;
                }
            }
            __builtin_amdgcn_s_setprio(0);

            // exp2 + per-lane row-sum (each lane owns q=q16, keys quad*4+r)
            #pragma unroll
            for (int g = 0; g < 2; g++)
                #pragma unroll
                for (int nt4 = 0; nt4 < 4; nt4++) {
                    s[g][nt4].x = fexp2(s[g][nt4].x - EXP_BIAS_);
                    s[g][nt4].y = fexp2(s[g][nt4].y - EXP_BIAS_);
                    s[g][nt4].z = fexp2(s[g][nt4].z - EXP_BIAS_);
                    s[g][nt4].w = fexp2(s[g][nt4].w - EXP_BIAS_);
                    lr[g] += (s[g][nt4].x + s[g][nt4].y) + (s[g][nt4].z + s[g][nt4].w);
                }

            // hoisted V-frags for this half (c = 2*hh + c2)
            s16x8 vf[2][3];
            #pragma unroll
            for (int c2 = 0; c2 < 2; c2++)
                #pragma unroll
                for (int dt = 0; dt < 3; dt++)
                    vf[c2][dt] = *(const s16x8*)&Vt[cur][dt * 16 + q16][(2 * hh + c2) * 32 + quad * 8];

            #pragma unroll
            for (int g = 0; g < 2; g++) {
                // pack P pairs -> 4 x ds_write_b64 into Ps[wid][q][k]
                #pragma unroll
                for (int n2 = 0; n2 < 4; n2++) {
                    unsigned lo = pk_bf16(s[g][n2].x, s[g][n2].y);
                    unsigned hi = pk_bf16(s[g][n2].z, s[g][n2].w);
                    uint2 pkw = { lo, hi };
                    *(uint2*)&Ps[wid][q16][n2 * 16 + quad * 4] = pkw;
                }
                #pragma unroll
                for (int c2 = 0; c2 < 2; c2++) {
                    s16x8 pfr = *(const s16x8*)&Ps[wid][q16][c2 * 32 + quad * 8];
                    __builtin_amdgcn_s_setprio(1);
                    #pragma unroll
                    for (int dt = 0; dt < 3; dt++)
                        o[g][dt] = __builtin_amdgcn_mfma_f32_16x16x32_bf16(vf[c2][dt], pfr, o[g][dt], 0, 0, 0);
                    __builtin_amdgcn_s_setprio(0);
                }
            }
        }

        // (3) write prefetch to buffer cur^1
        if (kt < 7) {
            int nb = cur ^ 1;
            *(int4*)&Ks[nb][kr][koff]      = kpf0;
            *(int4*)&Ks[nb][kr][koff + 8]  = kpf1;
            *(int4*)&Ks[nb][kr][koff + 16] = kpf2;
            *(int4*)&Vt[nb][vr0][vc0]      = vpf0;
            *(int4*)&Vt[nb][vr0 + 16][vc0] = vpf1;
            *(int4*)&Vt[nb][vr0 + 32][vc0] = vpf2;
        }
        // (4) one barrier per iteration
        __syncthreads();
    }

    // full row-sum: reduce across the 4 quads (lanes q16 + 16*quad)
    #pragma unroll
    for (int g = 0; g < 2; g++) {
        lr[g] += __shfl_xor(lr[g], 16);
        lr[g] += __shfl_xor(lr[g], 32);
    }

    // epilogue: o[g][dt][r] = O[q=q16][d=dt*16+quad*4+r] -> Kflat rows, b64 writes
    #pragma unroll
    for (int g = 0; g < 2; g++) {
        float inv = __builtin_amdgcn_rcpf(lr[g]);
        #pragma unroll
        for (int dt = 0; dt < 3; dt++) {
            f32x4 a = o[g][dt];
            unsigned u0 = (unsigned)f2bf(a.x * inv) | ((unsigned)f2bf(a.y * inv) << 16);
            unsigned u1 = (unsigned)f2bf(a.z * inv) | ((unsigned)f2bf(a.w * inv) << 16);
            uint2 pkw = { u0, u1 };
            *(uint2*)&Kflat[wid * 32 + g * 16 + q16][dt * 16 + quad * 4] = pkw;
        }
    }
    __syncthreads();

    {
        int r = tid >> 1, off = (tid & 1) * 24;
        unsigned short* dst = ao + ((size_t)b * 1024 + qt * 128 + r) * 384 + h * 48 + off;
        *(int4*)dst        = *(const int4*)&Kflat[r][off];
        *(int4*)(dst + 8)  = *(const int4*)&Kflat[r][off + 8];
        *(int4*)(dst + 16) = *(const int4*)&Kflat[r][off + 16];
    }
}

// ---------------------------------------------------------------------------
// Kernel 4: proj GEMM 64x64 tile, BK=96 + residual. Grid (128, 6) = 768 blocks.
// ---------------------------------------------------------------------------
__global__ __launch_bounds__(256) void proj_mfma(const unsigned short* __restrict__ ao,
                                                 const unsigned short* __restrict__ w,
                                                 const float* __restrict__ x,
                                                 float* __restrict__ out) {
    __shared__ __align__(16) unsigned short As[64][104];
    __shared__ __align__(16) unsigned short Bs[64][104];

    int tid = threadIdx.x;
    int m0 = blockIdx.x * 64;
    int j0 = blockIdx.y * 64;
    int lane = tid & 63, wid = tid >> 6;
    int wr = wid >> 1, wc = wid & 1;
    int q16 = lane & 15, quad = lane >> 4;

    f32x4 acc[2][2] = {};

    // staging: 4 threads per row, 24 cols (3 int4) each
    const int srow = tid >> 2, sc = (tid & 3) * 24;
    for (int k0 = 0; k0 < 384; k0 += 96) {
        const unsigned short* ga = &ao[(size_t)(m0 + srow) * 384 + k0 + sc];
        const unsigned short* gb = &w[(size_t)(j0 + srow) * 384 + k0 + sc];
        #pragma unroll
        for (int u = 0; u < 3; u++) *(int4*)&As[srow][sc + u * 8] = *(const int4*)(ga + u * 8);
        #pragma unroll
        for (int u = 0; u < 3; u++) *(int4*)&Bs[srow][sc + u * 8] = *(const int4*)(gb + u * 8);
        __syncthreads();
        #pragma unroll
        for (int s = 0; s < 3; s++) {
            s16x8 af[2], bfr[2];
            #pragma unroll
            for (int mi = 0; mi < 2; mi++) af[mi]  = *(const s16x8*)&As[wr * 32 + mi * 16 + q16][s * 32 + quad * 8];
            #pragma unroll
            for (int ni = 0; ni < 2; ni++) bfr[ni] = *(const s16x8*)&Bs[wc * 32 + ni * 16 + q16][s * 32 + quad * 8];
            #pragma unroll
            for (int mi = 0; mi < 2; mi++)
                #pragma unroll
                for (int ni = 0; ni < 2; ni++)
                    acc[mi][ni] = __builtin_amdgcn_mfma_f32_16x16x32_bf16(af[mi], bfr[ni], acc[mi][ni], 0, 0, 0);
        }
        __syncthreads();
    }

    #pragma unroll
    for (int mi = 0; mi < 2; mi++) {
        int m_base = m0 + wr * 32 + mi * 16 + quad * 4;
        int bb = m_base >> 10;
        int nn = m_base & 1023;
        #pragma unroll
        for (int ni = 0; ni < 2; ni++) {
            int col = j0 + wc * 32 + ni * 16 + q16;
            size_t idx = ((size_t)bb * 384 + col) * 1024 + nn;
            float4 xr = *(const float4*)&x[idx];
            f32x4 a = acc[mi][ni];
            float4 ov = { xr.x + a.x, xr.y + a.y, xr.z + a.z, xr.w + a.w };
            *(float4*)&out[idx] = ov;
        }
    }
}

// ---------------------------------------------------------------------------
extern "C" void kernel_launch(void* const* d_in, const int* in_sizes, int n_in,
                              void* d_out, int out_size, void* d_ws, size_t ws_size,
                              hipStream_t stream) {
    const float* x     = (const float*)d_in[0];
    const float* wqkv  = (const float*)d_in[1];
    const float* wproj = (const float*)d_in[2];
    const float* lnw   = (const float*)d_in[3];
    const float* lnb   = (const float*)d_in[4];
    float* out = (float*)d_out;

    unsigned short* ws16 = (unsigned short*)d_ws;
    size_t off = 0;
    unsigned short* t_bf  = ws16 + off; off += (size_t)8192 * 384;
    unsigned short* wq_bf = ws16 + off; off += (size_t)1152 * 384;
    unsigned short* wp_bf = ws16 + off; off += (size_t)384 * 384;
    unsigned short* qn    = ws16 + off; off += (size_t)8192 * 384;   // [b,n,384] pre-scaled by SCALE*log2e
    unsigned short* kn    = ws16 + off; off += (size_t)8192 * 384;   // [b,n,384]
    unsigned short* vt    = ws16 + off; off += (size_t)64 * 48 * 1024; // [b,h,d,n]
    unsigned short* ao_bf = ws16 + off; off += (size_t)8192 * 384;

    ln_cvt_kernel<<<512, 256, 0, stream>>>(x, lnw, lnb, wqkv, wproj, t_bf, wq_bf, wp_bf);
    qkv_mfma<<<dim3(64, 9), 256, 0, stream>>>(t_bf, wq_bf, qn, kn, vt);
    attn_mfma<<<dim3(8, NH_, B_), 256, 0, stream>>>(qn, kn, vt, ao_bf);
    proj_mfma<<<dim3(128, 6), 256, 0, stream>>>(ao_bf, wp_bf, x, out);
}